// Round 6
// baseline (636.939 us; speedup 1.0000x reference)
//
#include <hip/hip_runtime.h>
#include <cstdint>

// Problem constants
#define NN 8192      // nodes
#define FF 512       // input features
#define FO 64        // per-head output features
#define NH 8         // heads
#define LDVT 8192    // V_t row stride (elements) -- V_t is (640 rows x 8192 k) bf16
#define LDYE 520     // Y row stride (elements): 512 numerator cols + 8 denom cols
#define YPART (8192 * 520)
#define SPLITK 3

typedef __attribute__((ext_vector_type(8))) __bf16 bf16x8;
typedef __attribute__((ext_vector_type(4))) float f32x4;

__device__ __forceinline__ unsigned short f2bf(float f) {
    // round-to-nearest-even f32 -> bf16 bits
    unsigned int u = __float_as_uint(f);
    u += 0x7fffu + ((u >> 16) & 1u);
    return (unsigned short)(u >> 16);
}

__device__ __forceinline__ void gload16(const void* g, void* l) {
    // async global->LDS, 16B per lane (emits global_load_lds_dwordx4)
    __builtin_amdgcn_global_load_lds(
        (const __attribute__((address_space(1))) unsigned int*)g,
        (__attribute__((address_space(3))) unsigned int*)l,
        16, 0, 0);
}

// ---------------------------------------------------------------------------
// K0: convert A (fp32, {0.0,1.0} -- exact in bf16 via truncation) to bf16.
// ---------------------------------------------------------------------------
__global__ __launch_bounds__(256) void k_convA(const uint4* __restrict__ A,
                                               uint4* __restrict__ Ab) {
    size_t i = (size_t)blockIdx.x * 256 + threadIdx.x;
    uint4 a = A[2 * i];
    uint4 b = A[2 * i + 1];
    uint4 o;
    o.x = (a.x >> 16) | (a.y & 0xffff0000u);
    o.y = (a.z >> 16) | (a.w & 0xffff0000u);
    o.z = (b.x >> 16) | (b.y & 0xffff0000u);
    o.w = (b.z >> 16) | (b.w & 0xffff0000u);
    Ab[i] = o;
}

// ---------------------------------------------------------------------------
// K0b: prep for k_wx. Blocks [0,2048): X fp32 -> bf16 (RNE), 8 elems/thread.
// Blocks [2048,2056): kernels (h,f,o) fp32 -> Kt (h,o,f) bf16 (tiny).
// ---------------------------------------------------------------------------
__global__ __launch_bounds__(256) void k_prep(const float* __restrict__ X,
                                              const float* __restrict__ Kw,
                                              unsigned short* __restrict__ Xb,
                                              unsigned short* __restrict__ Ktb) {
    const int b = blockIdx.x;
    const int t = threadIdx.x;
    if (b < 2048) {
        size_t base = ((size_t)b * 256 + t) * 8;
        float4 a = *(const float4*)(X + base);
        float4 c = *(const float4*)(X + base + 4);
        ushort4 o0, o1;
        o0.x = f2bf(a.x); o0.y = f2bf(a.y); o0.z = f2bf(a.z); o0.w = f2bf(a.w);
        o1.x = f2bf(c.x); o1.y = f2bf(c.y); o1.z = f2bf(c.z); o1.w = f2bf(c.w);
        *(ushort4*)(Xb + base) = o0;
        *(ushort4*)(Xb + base + 4) = o1;
    } else {
        int h = b - 2048;
        for (int e = t; e < FF * FO; e += 256) {
            int o = e >> 9, f = e & 511;   // write coalesced in f
            Ktb[(size_t)h * FF * FO + e] = f2bf(Kw[(size_t)h * FF * FO + (size_t)f * FO + o]);
        }
    }
}

// ---------------------------------------------------------------------------
// K1: per (head, 128-node tile): WX = Xb @ Kt^T via bf16 MFMA (K=512),
// s2 = WX . a2 (in-register shfl_xor reduce), e = exp(s2),
// V_t[h*64+o][n] = bf16(e*WX[n][o]), V_t[512+h][n] = bf16(e).
// 4 waves; wave tile 32 rows x 64 cols = 2x4 MFMA tiles (acc 32 AGPR).
// ---------------------------------------------------------------------------
union WxSmem {
    struct { unsigned short Xs[4096]; unsigned short Ks[2048]; } s;  // 12 KB granule layout
    unsigned short Vs[64][136];                                      // 17.4 KB transpose buf
};

__global__ __launch_bounds__(256) void k_wx(const unsigned short* __restrict__ Xb,
                                            const unsigned short* __restrict__ Ktb,
                                            const float* __restrict__ Aw,
                                            unsigned short* __restrict__ Vt) {
    __shared__ WxSmem sm;
    const int t = threadIdx.x;
    const int n0 = blockIdx.x * 128;
    const int h = blockIdx.y;
    const int lane = t & 63, w = t >> 6;
    const int quad = lane >> 4, l15 = lane & 15;

    // staging: Xs granule g = kq*128 + row  (row = g&127, kq = g>>7)
    const unsigned short* xS0 = Xb + (size_t)(n0 + (t & 127)) * FF + (t >> 7) * 8;
    const unsigned short* xS1 = Xb + (size_t)(n0 + ((t + 256) & 127)) * FF + ((t + 256) >> 7) * 8;
    unsigned short* xD0 = sm.s.Xs + t * 8;
    unsigned short* xD1 = sm.s.Xs + (t + 256) * 8;
    // Ks granule g = kq*64 + orow  (orow = g&63, kq = g>>6)
    const unsigned short* kS = Ktb + (size_t)h * FF * FO + (size_t)(t & 63) * FF + (t >> 6) * 8;
    unsigned short* kD = sm.s.Ks + t * 8;

    const bf16x8* aF[2];
    const bf16x8* bF[4];
    for (int i = 0; i < 2; ++i)
        aF[i] = (const bf16x8*)(sm.s.Xs + (size_t)(quad * 128 + w * 32 + i * 16 + l15) * 8);
    for (int j = 0; j < 4; ++j)
        bF[j] = (const bf16x8*)(sm.s.Ks + (size_t)(quad * 64 + j * 16 + l15) * 8);

    f32x4 acc[2][4] = {};
    for (int f0 = 0; f0 < FF; f0 += 32) {
        gload16(xS0 + f0, xD0);
        gload16(xS1 + f0, xD1);
        gload16(kS + f0, kD);
        __syncthreads();
        bf16x8 av[2], bv[4];
        for (int i = 0; i < 2; ++i) av[i] = aF[i][0];
        for (int j = 0; j < 4; ++j) bv[j] = bF[j][0];
        for (int i = 0; i < 2; ++i)
            for (int j = 0; j < 4; ++j)
                acc[i][j] = __builtin_amdgcn_mfma_f32_16x16x32_bf16(av[i], bv[j], acc[i][j], 0, 0, 0);
        __syncthreads();
    }

    // s2 per node row; C layout: col = l15 (+16j), row = quad*4 + r (+16i + 32w)
    float a2v[4];
    for (int j = 0; j < 4; ++j) a2v[j] = Aw[h * 128 + 64 + j * 16 + l15];
    float ex[2][4];
    for (int i = 0; i < 2; ++i)
        for (int r = 0; r < 4; ++r) {
            float p = acc[i][0][r] * a2v[0] + acc[i][1][r] * a2v[1]
                    + acc[i][2][r] * a2v[2] + acc[i][3][r] * a2v[3];
            p += __shfl_xor(p, 1);
            p += __shfl_xor(p, 2);
            p += __shfl_xor(p, 4);
            p += __shfl_xor(p, 8);
            ex[i][r] = __expf(p);
        }

    // scale + transpose through LDS (loop-end barrier protects Xs/Ks reuse)
    for (int i = 0; i < 2; ++i)
        for (int j = 0; j < 4; ++j)
            for (int r = 0; r < 4; ++r) {
                int row = w * 32 + i * 16 + quad * 4 + r;
                int col = j * 16 + l15;
                sm.Vs[col][row] = f2bf(ex[i][r] * acc[i][j][r]);
            }
    __syncthreads();
    // 64 o-rows x 128 nodes = 1024 uint4 (R4 bug was j2<2)
    for (int j2 = 0; j2 < 4; ++j2) {
        int vid = t + j2 * 256;           // 0..1023
        int o = vid >> 4, c = vid & 15;   // o: 0..63, c: 0..15 (8 nodes each)
        *(uint4*)(Vt + (size_t)(h * 64 + o) * LDVT + n0 + c * 8) =
            *(const uint4*)&sm.Vs[o][c * 8];
    }
    if (l15 == 0) {
        for (int i = 0; i < 2; ++i)
            for (int r = 0; r < 4; ++r) {
                int row = w * 32 + i * 16 + quad * 4 + r;
                Vt[(size_t)(512 + h) * LDVT + n0 + row] = f2bf(ex[i][r]);
            }
    }
    // rows 520..639 of V_t stay poisoned -> those Y cols never stored (guard).
}

// ---------------------------------------------------------------------------
// K2: Y = A_bf16 (8192x8192) @ V_t^T (8192x640), bf16 MFMA, fp32 acc.
// BM=128, BN=160, BK=64 (R6: doubled to halve barrier-drain count; 40 MFMA
// per barrier pair). 4 waves 2x2; wave tile 64x80 (4x5 tiles, 80 AGPR).
// LDS 36 KB -> 3 blocks/CU (matches the 148-reg residency cap).
// Split-K = 3 -> 768 blocks = 3/CU exactly.
// XCD swizzle: 4 ct-friends of each A stripe land on one XCD, adjacent
// dispatch -> A re-reads hit XCD-local L2 (R5: FETCH 500->162 MB).
// ---------------------------------------------------------------------------
__global__ __launch_bounds__(256) void k_gemm(const unsigned short* __restrict__ Ab,
                                              const unsigned short* __restrict__ Vt,
                                              float* __restrict__ Y) {
    __shared__ unsigned short As[8192];    // 128 rows * 64 k, 16 KB (1024 granules)
    __shared__ unsigned short Bs[10240];   // 160 rows * 64 k, 20 KB (1280 granules)
    const int t = threadIdx.x;
    // swizzled decode: grid = 768
    const int id = blockIdx.x;
    const int xcd = id & 7;
    const int u = id >> 3;                 // 0..95
    const int ct = u & 3;                  // 0..3
    const int rp = ((u >> 2) << 3) | xcd;  // 0..191
    const int rt = rp & 63;                // 0..63
    const int part = rp >> 6;              // 0..2
    const int ks0 = (part * 128) / SPLITK;       // 128 iters of BK=64 total
    const int ks1 = ((part + 1) * 128) / SPLITK;

    // A staging: granule g = kq*128 + row (kq=g>>7 in 0..7, row=g&127),
    // thread t covers g = t + 256j, j=0..3. Dest = As + g*16B (wave-uniform
    // base + lane*16 within each wave -- required by global_load_lds).
    const unsigned short* aS[4];
    unsigned short* aD[4];
    for (int j = 0; j < 4; ++j) {
        int g = t + j * 256;
        aS[j] = Ab + ((size_t)(rt * 128 + (g & 127)) << 13) + (g >> 7) * 8;
        aD[j] = As + g * 8;
    }
    // B staging: granule g = kq*160 + n (kq=g/160 in 0..7, n=g%160),
    // thread t covers g = t + 256j, j=0..4 (1280 = 5*256 exactly).
    const unsigned short* bS[5];
    unsigned short* bD[5];
    for (int j = 0; j < 5; ++j) {
        int g = t + j * 256;
        int n = g % 160, kq = g / 160;
        bS[j] = Vt + ((size_t)(ct * 160 + n) << 13) + kq * 8;
        bD[j] = Bs + g * 8;
    }

    const int lane = t & 63;
    const int w = t >> 6;
    const int wm = w >> 1, wn = w & 1;
    const int quad = lane >> 4, l15 = lane & 15;

    // fragment base (h2=0 half); h2=1 adds 4096 (A) / 5120 (B) shorts
    const unsigned short* aF[4];
    const unsigned short* bF[5];
    for (int i = 0; i < 4; ++i)
        aF[i] = As + (size_t)(quad * 128 + wm * 64 + i * 16 + l15) * 8;
    for (int j = 0; j < 5; ++j)
        bF[j] = Bs + (size_t)(quad * 160 + wn * 80 + j * 16 + l15) * 8;

    f32x4 acc[4][5] = {};

    for (int ks = ks0; ks < ks1; ++ks) {
        const size_t ko = (size_t)ks * 64;
        for (int j = 0; j < 4; ++j) gload16(aS[j] + ko, aD[j]);
        for (int j = 0; j < 5; ++j) gload16(bS[j] + ko, bD[j]);
        __syncthreads();   // drains vmcnt (barrier semantics)
#pragma unroll
        for (int h2 = 0; h2 < 2; ++h2) {
            bf16x8 av[4], bv[5];
            for (int i = 0; i < 4; ++i)
                av[i] = *(const bf16x8*)(aF[i] + h2 * 4096);
            for (int j = 0; j < 5; ++j)
                bv[j] = *(const bf16x8*)(bF[j] + h2 * 5120);
            for (int i = 0; i < 4; ++i)
                for (int j = 0; j < 5; ++j)
                    acc[i][j] = __builtin_amdgcn_mfma_f32_16x16x32_bf16(av[i], bv[j], acc[i][j], 0, 0, 0);
        }
        __syncthreads();   // protect LDS from next iteration's staging
    }

    // C/D layout: col = lane&15, row = (lane>>4)*4 + reg
    float* Yp = Y + (size_t)part * YPART;
    for (int i = 0; i < 4; ++i) {
        int row = rt * 128 + wm * 64 + i * 16 + quad * 4;
        for (int j = 0; j < 5; ++j) {
            int col = ct * 160 + wn * 80 + j * 16 + l15;
            if (col < 520) {
                for (int r = 0; r < 4; ++r)
                    Yp[(size_t)(row + r) * LDYE + col] = acc[i][j][r];
            }
        }
    }
}

// ---------------------------------------------------------------------------
// K3: out[n, h*64+o] = relu( sum_p Ynum / sum_p Yden )
// ---------------------------------------------------------------------------
__global__ __launch_bounds__(256) void k_epi(const float* __restrict__ Y,
                                             float* __restrict__ out) {
    int idx = blockIdx.x * 256 + threadIdx.x;   // one float4 of out each
    int n = idx >> 7;
    int c = (idx & 127) * 4;
    int h = c >> 6;
    float4 u = {0.f, 0.f, 0.f, 0.f};
    float den = 0.f;
    const float* yp = Y + (size_t)n * LDYE;
#pragma unroll
    for (int p = 0; p < SPLITK; ++p) {
        float4 v = *(const float4*)(yp + c);
        u.x += v.x; u.y += v.y; u.z += v.z; u.w += v.w;
        den += yp[512 + h];
        yp += (size_t)YPART;
    }
    float inv = 1.0f / den;
    float4 o;
    o.x = fmaxf(u.x * inv, 0.f);
    o.y = fmaxf(u.y * inv, 0.f);
    o.z = fmaxf(u.z * inv, 0.f);
    o.w = fmaxf(u.w * inv, 0.f);
    *(float4*)(out + (size_t)n * 512 + c) = o;
}

extern "C" void kernel_launch(void* const* d_in, const int* in_sizes, int n_in,
                              void* d_out, int out_size, void* d_ws, size_t ws_size,
                              hipStream_t stream) {
    const float* X  = (const float*)d_in[0];   // (8192, 512)
    const float* A  = (const float*)d_in[1];   // (8192, 8192)
    const float* Kw = (const float*)d_in[2];   // (8, 512, 64)
    const float* Aw = (const float*)d_in[3];   // (8, 128)
    float* out = (float*)d_out;                // (8192, 512)
    char* ws = (char*)d_ws;
    // ws layout: Ab 128 MiB | Vt 10 MiB | Yb 3*16.25 MiB (total ~187 MiB).
    // Xb (8 MiB) + Ktb (0.5 MiB) ALIAS the head of Yb: consumed by k_wx
    // before k_gemm overwrites every Yb byte (all cols<520 stored, all parts).
    unsigned short* Ab = (unsigned short*)ws;
    unsigned short* Vt = (unsigned short*)(ws + (size_t)134217728);
    float* Yb = (float*)(ws + (size_t)134217728 + (size_t)10485760);
    unsigned short* Xb = (unsigned short*)Yb;
    unsigned short* Ktb = Xb + (size_t)NN * FF;

    k_convA<<<dim3(32768), dim3(256), 0, stream>>>((const uint4*)A, (uint4*)Ab);
    k_prep<<<dim3(2056), dim3(256), 0, stream>>>(X, Kw, Xb, Ktb);
    k_wx<<<dim3(64, 8), dim3(256), 0, stream>>>(Xb, Ktb, Aw, Vt);
    k_gemm<<<dim3(768), dim3(256), 0, stream>>>(Ab, Vt, Yb);
    k_epi<<<dim3(4096), dim3(256), 0, stream>>>(Yb, out);
}

// Round 7
// 511.905 us; speedup vs baseline: 1.2443x; 1.2443x over previous
//
#include <hip/hip_runtime.h>
#include <cstdint>

// Problem constants
#define NN 8192      // nodes
#define FF 512       // input features
#define FO 64        // per-head output features
#define NH 8         // heads
#define LDYE 520     // Y row stride: 512 numerator cols + 8 denom cols
#define YPART (8192 * 520)
#define SPLITK 3

// Tiled fp8 layouts (k-major 16-byte granules, in exact staging order):
//  Ab: granule G = (rt*512 + k16)*128 + row, 16 B = A[rt*128+row][k16*16..+16]
//  Vt: granule H = k16*640 + vrow,          16 B = V[vrow][k16*16..+16]
//  (vrow: h*64+o for o<64 per head; 512+h = e-row; 520..639 unused/garbage)

typedef __attribute__((ext_vector_type(8))) __bf16 bf16x8;
typedef __attribute__((ext_vector_type(4))) float f32x4;

__device__ __forceinline__ unsigned short f2bf(float f) {
    unsigned int u = __float_as_uint(f);
    u += 0x7fffu + ((u >> 16) & 1u);
    return (unsigned short)(u >> 16);
}

__device__ __forceinline__ void gload16(const void* g, void* l) {
    __builtin_amdgcn_global_load_lds(
        (const __attribute__((address_space(1))) unsigned int*)g,
        (__attribute__((address_space(3))) unsigned int*)l,
        16, 0, 0);
}

// ---------------------------------------------------------------------------
// K0: A fp32 {0.0,1.0} -> fp8 e4m3 (0x00 / 0x38 -- exact), TILED layout.
// Block b: rt = b>>8, k16 pair = (b&255)*2; thread t: row = t>>1, half = t&1.
// Reads 128 B/row-pair contiguous; writes 16 B granules.
// ---------------------------------------------------------------------------
__global__ __launch_bounds__(256) void k_convA8(const float* __restrict__ A,
                                                unsigned char* __restrict__ Ab) {
    const int b = blockIdx.x, t = threadIdx.x;
    const int rt = b >> 8;
    const int k16 = ((b & 255) << 1) | (t & 1);
    const int row = t >> 1;
    const uint4* src = (const uint4*)(A + (((size_t)(rt * 128 + row)) << 13) + k16 * 16);
    uint4 f0 = src[0], f1 = src[1], f2 = src[2], f3 = src[3];
    // 1.0f = 0x3F800000 -> (>>22)&0x38 = 0x38 (e4m3 1.0); 0.0f -> 0x00
#define PK8(v) (((v.x >> 22) & 0x38u) | (((v.y >> 22) & 0x38u) << 8) | \
                (((v.z >> 22) & 0x38u) << 16) | (((v.w >> 22) & 0x38u) << 24))
    uint4 o = {PK8(f0), PK8(f1), PK8(f2), PK8(f3)};
#undef PK8
    size_t G = (((size_t)(rt * 512 + k16)) << 7) + row;
    *(uint4*)(Ab + (G << 4)) = o;
}

// ---------------------------------------------------------------------------
// K0b: X fp32->bf16 (blocks <2048); kernels (h,f,o)->Kt (h,o,f) bf16.
// ---------------------------------------------------------------------------
__global__ __launch_bounds__(256) void k_prep(const float* __restrict__ X,
                                              const float* __restrict__ Kw,
                                              unsigned short* __restrict__ Xb,
                                              unsigned short* __restrict__ Ktb) {
    const int b = blockIdx.x;
    const int t = threadIdx.x;
    if (b < 2048) {
        size_t base = ((size_t)b * 256 + t) * 8;
        float4 a = *(const float4*)(X + base);
        float4 c = *(const float4*)(X + base + 4);
        ushort4 o0, o1;
        o0.x = f2bf(a.x); o0.y = f2bf(a.y); o0.z = f2bf(a.z); o0.w = f2bf(a.w);
        o1.x = f2bf(c.x); o1.y = f2bf(c.y); o1.z = f2bf(c.z); o1.w = f2bf(c.w);
        *(ushort4*)(Xb + base) = o0;
        *(ushort4*)(Xb + base + 4) = o1;
    } else {
        int h = b - 2048;
        for (int e = t; e < FF * FO; e += 256) {
            int o = e >> 9, f = e & 511;
            Ktb[(size_t)h * FF * FO + e] = f2bf(Kw[(size_t)h * FF * FO + (size_t)f * FO + o]);
        }
    }
}

// ---------------------------------------------------------------------------
// K1: per (head, 128-node tile): WX = Xb @ Kt^T bf16 MFMA (K=512),
// s2 = WX.a2 (shfl_xor), e = exp(s2); emit fp8 V into tiled Vt:
// Vt granule ((n0>>4)+k16o)*640 + h*64+o = fp8(e*WX) for 16 nodes.
// ---------------------------------------------------------------------------
union WxSmem {
    struct { unsigned short Xs[4096]; unsigned short Ks[2048]; } s;  // 12 KB
    unsigned char Vs[64][144];                                       // 9 KB (o x node)
};

__global__ __launch_bounds__(256) void k_wx(const unsigned short* __restrict__ Xb,
                                            const unsigned short* __restrict__ Ktb,
                                            const float* __restrict__ Aw,
                                            unsigned char* __restrict__ Vt) {
    __shared__ WxSmem sm;
    const int t = threadIdx.x;
    const int n0 = blockIdx.x * 128;
    const int h = blockIdx.y;
    const int lane = t & 63, w = t >> 6;
    const int quad = lane >> 4, l15 = lane & 15;

    const unsigned short* xS0 = Xb + (size_t)(n0 + (t & 127)) * FF + (t >> 7) * 8;
    const unsigned short* xS1 = Xb + (size_t)(n0 + ((t + 256) & 127)) * FF + ((t + 256) >> 7) * 8;
    unsigned short* xD0 = sm.s.Xs + t * 8;
    unsigned short* xD1 = sm.s.Xs + (t + 256) * 8;
    const unsigned short* kS = Ktb + (size_t)h * FF * FO + (size_t)(t & 63) * FF + (t >> 6) * 8;
    unsigned short* kD = sm.s.Ks + t * 8;

    const bf16x8* aF[2];
    const bf16x8* bF[4];
    for (int i = 0; i < 2; ++i)
        aF[i] = (const bf16x8*)(sm.s.Xs + (size_t)(quad * 128 + w * 32 + i * 16 + l15) * 8);
    for (int j = 0; j < 4; ++j)
        bF[j] = (const bf16x8*)(sm.s.Ks + (size_t)(quad * 64 + j * 16 + l15) * 8);

    f32x4 acc[2][4] = {};
    for (int f0 = 0; f0 < FF; f0 += 32) {
        gload16(xS0 + f0, xD0);
        gload16(xS1 + f0, xD1);
        gload16(kS + f0, kD);
        __syncthreads();
        bf16x8 av[2], bv[4];
        for (int i = 0; i < 2; ++i) av[i] = aF[i][0];
        for (int j = 0; j < 4; ++j) bv[j] = bF[j][0];
        for (int i = 0; i < 2; ++i)
            for (int j = 0; j < 4; ++j)
                acc[i][j] = __builtin_amdgcn_mfma_f32_16x16x32_bf16(av[i], bv[j], acc[i][j], 0, 0, 0);
        __syncthreads();
    }

    // s2; C layout: col = l15 + 16j, row = w*32 + i*16 + quad*4 + r
    float a2v[4];
    for (int j = 0; j < 4; ++j) a2v[j] = Aw[h * 128 + 64 + j * 16 + l15];
    float ex[2][4];
    for (int i = 0; i < 2; ++i)
        for (int r = 0; r < 4; ++r) {
            float p = acc[i][0][r] * a2v[0] + acc[i][1][r] * a2v[1]
                    + acc[i][2][r] * a2v[2] + acc[i][3][r] * a2v[3];
            p += __shfl_xor(p, 1);
            p += __shfl_xor(p, 2);
            p += __shfl_xor(p, 4);
            p += __shfl_xor(p, 8);
            ex[i][r] = __expf(p);
        }

    // fp8 convert + transpose: 4 rows (r=0..3) pack into one 32-bit LDS write
    for (int i = 0; i < 2; ++i)
        for (int j = 0; j < 4; ++j) {
            int rowb = w * 32 + i * 16 + quad * 4;
            int col = j * 16 + l15;
            unsigned u = __builtin_amdgcn_cvt_pk_fp8_f32(
                ex[i][0] * acc[i][j][0], ex[i][1] * acc[i][j][1], 0, false);
            u = __builtin_amdgcn_cvt_pk_fp8_f32(
                ex[i][2] * acc[i][j][2], ex[i][3] * acc[i][j][3], (int)u, true);
            *(unsigned*)&sm.Vs[col][rowb] = u;
        }
    __syncthreads();
    // writeback: 64 o-rows x 128 nodes = 8192 B = 512 uint4 = 2/thread
    for (int j2 = 0; j2 < 2; ++j2) {
        int vid = t + j2 * 256;            // 0..511
        int o = vid >> 3, k16o = vid & 7;  // o: 0..63, k16o: 0..7
        size_t H = (size_t)((n0 >> 4) + k16o) * 640 + h * 64 + o;
        *(uint4*)(Vt + (H << 4)) = *(const uint4*)&sm.Vs[o][k16o * 16];
    }
    if (l15 == 0) {  // e-row (vrow 512+h), one byte per node
        for (int i = 0; i < 2; ++i)
            for (int r = 0; r < 4; ++r) {
                int row = w * 32 + i * 16 + quad * 4 + r;
                unsigned u = __builtin_amdgcn_cvt_pk_fp8_f32(ex[i][r], ex[i][r], 0, false);
                size_t H = (size_t)((n0 >> 4) + (row >> 4)) * 640 + 512 + h;
                Vt[(H << 4) + (row & 15)] = (unsigned char)(u & 0xff);
            }
    }
}

// ---------------------------------------------------------------------------
// K2: Y = A_fp8 (8192x8192) @ V^T (8192x640), e4m3 MFMA 16x16x32, fp32 acc.
// BM=128, BN=160, BK=64 in 18 KB LDS (fp8 halves bytes/FLOP vs bf16).
// Tiled sources: every gload16 reads a CONTIGUOUS 1 KB/wave burst; per-iter
// tile is one linear 8 KB (A) / 10 KB (B) range -- no 16KB-stride scatter.
// 4 waves 2x2, wave tile 64x80 (acc 80 AGPR). Split-K=3, grid 768 = 3/CU.
// XCD swizzle keeps the 4 ct-friends of an A stripe on one XCD.
// ---------------------------------------------------------------------------
__global__ __launch_bounds__(256) void k_gemm(const unsigned char* __restrict__ Ab,
                                              const unsigned char* __restrict__ Vt,
                                              float* __restrict__ Y) {
    __shared__ unsigned char As[8192];    // kq(4) x row(128) x 16 B
    __shared__ unsigned char Bs[10240];   // kq(4) x n(160) x 16 B
    const int t = threadIdx.x;
    const int id = blockIdx.x;
    const int xcd = id & 7;
    const int u = id >> 3;
    const int ct = u & 3;
    const int rp = ((u >> 2) << 3) | xcd;
    const int rt = rp & 63;
    const int part = rp >> 6;
    const int ks0 = (part * 128) / SPLITK;        // 128 iters of 4 k16 each
    const int ks1 = ((part + 1) * 128) / SPLITK;

    // A staging: granule g = t + 256j (j<2), source linear: rt-block base +
    // ks*8192 + g*16. Dest = As + g*16.
    const unsigned char* aS0 = Ab + ((size_t)rt << 20) + (size_t)t * 16;
    const unsigned char* aS1 = aS0 + 4096;
    unsigned char* aD0 = As + t * 16;
    unsigned char* aD1 = aD0 + 4096;
    // B staging: granule g = t + 256j (j<2 full, j=2 half): source offset
    // within iter = (g/160)*10240 + (ct*160 + g%160)*16; iter adds 40960.
    const int g1 = t + 256, g2 = t + 512;
    const unsigned char* bS0 = Vt + (size_t)((t / 160) * 10240 + (ct * 160 + t % 160) * 16);
    const unsigned char* bS1 = Vt + (size_t)((g1 / 160) * 10240 + (ct * 160 + g1 % 160) * 16);
    const unsigned char* bS2 = Vt + (size_t)((g2 / 160) * 10240 + (ct * 160 + g2 % 160) * 16);
    unsigned char* bD0 = Bs + t * 16;
    unsigned char* bD1 = Bs + g1 * 16;
    unsigned char* bD2 = Bs + g2 * 16;

    const int lane = t & 63;
    const int w = t >> 6;
    const int wm = w >> 1, wn = w & 1;
    const int quad = lane >> 4, l15 = lane & 15;

    // fragment byte offsets (h2=0): 8B chunk q = quad (h2=1: q+4 -> +4096/+5120)
    int aOff[4], bOff[5];
    for (int i = 0; i < 4; ++i)
        aOff[i] = (quad >> 1) * 2048 + (quad & 1) * 8 + (wm * 64 + i * 16 + l15) * 16;
    for (int j = 0; j < 5; ++j)
        bOff[j] = (quad >> 1) * 2560 + (quad & 1) * 8 + (wn * 80 + j * 16 + l15) * 16;

    f32x4 acc[4][5] = {};

    for (int ks = ks0; ks < ks1; ++ks) {
        const size_t koA = (size_t)ks << 13;       // *8192
        const size_t koB = (size_t)ks * 40960;
        gload16(aS0 + koA, aD0);
        gload16(aS1 + koA, aD1);
        gload16(bS0 + koB, bD0);
        gload16(bS1 + koB, bD1);
        if (t < 128) gload16(bS2 + koB, bD2);
        __syncthreads();
#pragma unroll
        for (int h2 = 0; h2 < 2; ++h2) {
            long long av[4], bv[5];
            for (int i = 0; i < 4; ++i)
                av[i] = *(const long long*)(As + aOff[i] + h2 * 4096);
            for (int j = 0; j < 5; ++j)
                bv[j] = *(const long long*)(Bs + bOff[j] + h2 * 5120);
            for (int i = 0; i < 4; ++i)
                for (int j = 0; j < 5; ++j)
                    acc[i][j] = __builtin_amdgcn_mfma_f32_16x16x32_fp8_fp8(av[i], bv[j], acc[i][j], 0, 0, 0);
        }
        __syncthreads();
    }

    // C/D layout: col = lane&15, row = (lane>>4)*4 + reg
    float* Yp = Y + (size_t)part * YPART;
    for (int i = 0; i < 4; ++i) {
        int row = rt * 128 + wm * 64 + i * 16 + quad * 4;
        for (int j = 0; j < 5; ++j) {
            int col = ct * 160 + wn * 80 + j * 16 + l15;
            if (col < 520) {
                for (int r = 0; r < 4; ++r)
                    Yp[(size_t)(row + r) * LDYE + col] = acc[i][j][r];
            }
        }
    }
}

// ---------------------------------------------------------------------------
// K3: out[n, h*64+o] = relu( sum_p Ynum / sum_p Yden )
// ---------------------------------------------------------------------------
__global__ __launch_bounds__(256) void k_epi(const float* __restrict__ Y,
                                             float* __restrict__ out) {
    int idx = blockIdx.x * 256 + threadIdx.x;
    int n = idx >> 7;
    int c = (idx & 127) * 4;
    int h = c >> 6;
    float4 u = {0.f, 0.f, 0.f, 0.f};
    float den = 0.f;
    const float* yp = Y + (size_t)n * LDYE;
#pragma unroll
    for (int p = 0; p < SPLITK; ++p) {
        float4 v = *(const float4*)(yp + c);
        u.x += v.x; u.y += v.y; u.z += v.z; u.w += v.w;
        den += yp[512 + h];
        yp += (size_t)YPART;
    }
    float inv = 1.0f / den;
    float4 o;
    o.x = fmaxf(u.x * inv, 0.f);
    o.y = fmaxf(u.y * inv, 0.f);
    o.z = fmaxf(u.z * inv, 0.f);
    o.w = fmaxf(u.w * inv, 0.f);
    *(float4*)(out + (size_t)n * 512 + c) = o;
}

extern "C" void kernel_launch(void* const* d_in, const int* in_sizes, int n_in,
                              void* d_out, int out_size, void* d_ws, size_t ws_size,
                              hipStream_t stream) {
    const float* X  = (const float*)d_in[0];   // (8192, 512)
    const float* A  = (const float*)d_in[1];   // (8192, 8192)
    const float* Kw = (const float*)d_in[2];   // (8, 512, 64)
    const float* Aw = (const float*)d_in[3];   // (8, 128)
    float* out = (float*)d_out;                // (8192, 512)
    char* ws = (char*)d_ws;
    // ws: Ab 64 MiB | Vt 5 MiB | Yb 3*16.25 MiB  (~118 MiB total).
    // Xb (8 MiB) + Ktb (0.5 MiB) alias the head of Yb (consumed by k_wx
    // before k_gemm writes Yb).
    unsigned char* Ab = (unsigned char*)ws;
    unsigned char* Vt = (unsigned char*)(ws + (size_t)67108864);
    float* Yb = (float*)(ws + (size_t)67108864 + (size_t)5242880);
    unsigned short* Xb = (unsigned short*)Yb;
    unsigned short* Ktb = Xb + (size_t)NN * FF;

    k_convA8<<<dim3(16384), dim3(256), 0, stream>>>(A, Ab);
    k_prep<<<dim3(2056), dim3(256), 0, stream>>>(X, Kw, Xb, Ktb);
    k_wx<<<dim3(64, 8), dim3(256), 0, stream>>>(Xb, Ktb, Aw, Vt);
    k_gemm<<<dim3(768), dim3(256), 0, stream>>>(Ab, Vt, Yb);
    k_epi<<<dim3(4096), dim3(256), 0, stream>>>(Yb, out);
}